// Round 12
// baseline (1001.743 us; speedup 1.0000x reference)
//
#include <hip/hip_runtime.h>
#include <float.h>
#include <math.h>

#define NGR 64        // graphs
#define NPG0 1000     // original nodes per graph
#define HDIM 128
#define EG 16000      // edges per graph
#define NE (NGR*EG)   // 1,024,000
#define RPS 1008      // rp row stride
#define BNEPS 1e-5f
#define POOL_NB 16

// ---------------- invnorm of pool_w rows (6 layers) ----------------
__global__ void k_invnorm(const float* __restrict__ pw, float* __restrict__ invnorm){
  int i = blockIdx.x;                  // layer
  int t = threadIdx.x;                 // 128 threads
  float v = pw[i*HDIM + t];
  float s = v*v;
  #pragma unroll
  for(int o=32;o>0;o>>=1) s += __shfl_down(s, o, 64);
  __shared__ float red[2];
  if((t & 63)==0) red[t>>6] = s;
  __syncthreads();
  if(t==0) invnorm[i] = 1.0f / sqrtf(red[0]+red[1]);
}

// ---------------- build phase: per-graph-chunk LDS count + weighted degree ----------------
__global__ __launch_bounds__(256) void k_count0(const int* __restrict__ dst,
    const float* __restrict__ we, int* __restrict__ pcnt, float* __restrict__ pdeg){
  int g = blockIdx.x >> 2, sub = blockIdx.x & 3, t = threadIdx.x;
  __shared__ int   cnt[NPG0];
  __shared__ float degl[NPG0];
  for(int i=t;i<NPG0;i+=256){ cnt[i]=0; degl[i]=0.f; }
  __syncthreads();
  int base = g*EG + sub*4000;
  for(int idx=t; idx<4000; idx+=256){
    int e = base + idx;
    int ld = dst[e] - g*NPG0;
    atomicAdd(&cnt[ld], 1);
    atomicAdd(&degl[ld], we[e]);
  }
  __syncthreads();
  int p = blockIdx.x * NPG0;
  for(int i=t;i<NPG0;i+=256){ pcnt[p+i] = cnt[i]; pdeg[p+i] = degl[i]; }
}

__global__ __launch_bounds__(512) void k_scan0(const int* __restrict__ pcnt,
    const float* __restrict__ pdeg, int* __restrict__ rp, float* __restrict__ dinvz,
    float* __restrict__ gsc){
  int g = blockIdx.x, t = threadIdx.x;
  __shared__ int sc[2][1024];
  for(int i=t;i<1024;i+=512){
    int c = 0;
    if(i<NPG0){
      c = pcnt[(g*4+0)*NPG0+i] + pcnt[(g*4+1)*NPG0+i]
        + pcnt[(g*4+2)*NPG0+i] + pcnt[(g*4+3)*NPG0+i];
      float dg = pdeg[(g*4+0)*NPG0+i] + pdeg[(g*4+1)*NPG0+i]
               + pdeg[(g*4+2)*NPG0+i] + pdeg[(g*4+3)*NPG0+i];
      float dv = 1.0f / sqrtf(dg + 1.0f);
      dinvz[g*NPG0+i] = dv;
      gsc[g*NPG0+i]   = dv;      // layer-0 feature scale: val == 1
    }
    sc[0][i] = c;
  }
  __syncthreads();
  int buf = 0;
  for(int d=1; d<1024; d<<=1){
    for(int i=t;i<1024;i+=512){
      int v = sc[buf][i];
      if(i>=d) v += sc[buf][i-d];
      sc[buf^1][i] = v;
    }
    __syncthreads();
    buf ^= 1;
  }
  for(int i=t;i<=NPG0;i+=512) rp[g*RPS+i] = (i==0) ? 0 : sc[buf][i-1];
}

// ---------------- scatter: per-graph LDS cursor ----------------
// ec record = (float w)<<32 | src_orig  (static for whole run)
__global__ __launch_bounds__(1024) void k_scatter0(const int* __restrict__ src,
    const int* __restrict__ dst, const float* __restrict__ we,
    const int* __restrict__ rp, long long* __restrict__ ec){
  int g = blockIdx.x, t = threadIdx.x;
  __shared__ int cur[NPG0];
  for(int i=t;i<NPG0;i+=1024) cur[i] = rp[g*RPS+i];
  __syncthreads();
  int base = g*EG;
  for(int idx=t; idx<EG; idx+=1024){
    int e = base + idx;
    int ld = dst[e] - g*NPG0;
    int pos = atomicAdd(&cur[ld], 1);
    ec[(size_t)base + pos] = (((long long)__float_as_int(we[e]))<<32) | (unsigned)src[e];
  }
}

// ================= FUSED aggregation + GEMM =================
// Phase 1: each block aggregates its 64 A-tile rows directly into LDS
//   As[row] = dvd*( sum_e w*gsc[src]*h[src] + gsc[d]*h[d] )  (k_agg formula)
// Phase 2: tiled GEMM from resident As + staged Bs; epilogue bias+BN+ReLU,
//   scatter-write raw rows to horig, score via shfl-reduce.

// ---- layer 0: x has 64 cols, W is 64x128 fully LDS-resident (no compute barriers) ----
__global__ __launch_bounds__(256) void k_agemm0(
    const int* __restrict__ rp, const long long* __restrict__ ec,
    const float* __restrict__ dinvz, const float* __restrict__ gsc,
    const float* __restrict__ x, const float* __restrict__ Wm,
    const float* __restrict__ bias, const float* __restrict__ gamma,
    const float* __restrict__ beta, const float* __restrict__ mean,
    const float* __restrict__ var, const float* __restrict__ pw,
    const float* __restrict__ invn_p, float* __restrict__ hout,
    float* __restrict__ score){
  __shared__ float As[64*68];     // 64 rows x 64 k, stride 68 (16B-aligned rows)
  __shared__ float Bs[64*128];    // full W1
  int t = threadIdx.x;
  int wid = t >> 6, lane = t & 63;
  int qw = lane >> 4, sl16 = lane & 15;
  int r0 = blockIdx.x * 64;
  int g0 = r0 / 1000, bnd = (g0+1)*1000;
  // stage full W (loads overlap the phase-1 gathers; barrier below orders both)
  #pragma unroll
  for(int p=0;p<8;p++){
    int idx = p*256 + t;
    int kk = idx >> 5, cq = idx & 31;
    *(float4*)&Bs[kk*128 + cq*4] = *(const float4*)(Wm + (size_t)kk*128 + cq*4);
  }
  // phase 1: quarter-wave record split, 4 rows in flight per wave over 16 rows
  for(int jj = wid; jj < 64; jj += 4){
    int row = r0 + jj;
    int g = (row >= bnd) ? g0+1 : g0;
    int d = row;                       // layer 0: orig id == row
    int ld = row - g*1000;
    int e0 = rp[g*RPS+ld], e1 = rp[g*RPS+ld+1];
    float4 acc; acc.x=0.f; acc.y=0.f; acc.z=0.f; acc.w=0.f;
    for(int b=e0;b<e1;b+=64){
      int mm = e1-b; if(mm>64) mm=64;
      long long rec = (lane<mm) ? ec[(size_t)g*EG + b + lane] : 0;
      int   sl = (int)(rec & 0xffffffffLL);
      float cl = __int_as_float((int)(rec>>32)) * gsc[sl];
      long long pk = (((long long)__float_as_int(cl))<<32) | (unsigned)sl;
      int mr = (mm+31) & ~31;
      for(int j2=0;j2<mr;j2+=32){
        #pragma unroll
        for(int u=0;u<8;u++){
          long long p = __shfl(pk, j2 + 4*u + qw, 64);
          float c = __int_as_float((int)(p>>32));
          if(c != 0.f){
            int s = (int)(p & 0xffffffffLL);
            float4 hv = *(const float4*)(x + (size_t)s*64 + 4*sl16);
            acc.x += c*hv.x; acc.y += c*hv.y; acc.z += c*hv.z; acc.w += c*hv.w;
          }
        }
      }
    }
    acc.x += __shfl_xor(acc.x, 16, 64); acc.y += __shfl_xor(acc.y, 16, 64);
    acc.z += __shfl_xor(acc.z, 16, 64); acc.w += __shfl_xor(acc.w, 16, 64);
    acc.x += __shfl_xor(acc.x, 32, 64); acc.y += __shfl_xor(acc.y, 32, 64);
    acc.z += __shfl_xor(acc.z, 32, 64); acc.w += __shfl_xor(acc.w, 32, 64);
    if(qw==0){
      float dvd = dinvz[d], gsd = gsc[d];
      float4 hs = *(const float4*)(x + (size_t)d*64 + 4*sl16);
      float4 o;
      o.x = dvd*(acc.x + gsd*hs.x); o.y = dvd*(acc.y + gsd*hs.y);
      o.z = dvd*(acc.z + gsd*hs.z); o.w = dvd*(acc.w + gsd*hs.w);
      *(float4*)&As[jj*68 + 4*sl16] = o;
    }
  }
  __syncthreads();
  // phase 2: barrier-free GEMM (A and W fully resident)
  int tx = t & 31, ty = t >> 5;
  float acc2[8][4];
  #pragma unroll
  for(int j=0;j<8;j++){
    #pragma unroll
    for(int i=0;i<4;i++) acc2[j][i]=0.f;
  }
  #pragma unroll 4
  for(int kk=0;kk<64;kk+=4){
    float4 b0 = *(float4*)&Bs[(kk+0)*128 + tx*4];
    float4 b1 = *(float4*)&Bs[(kk+1)*128 + tx*4];
    float4 b2 = *(float4*)&Bs[(kk+2)*128 + tx*4];
    float4 b3 = *(float4*)&Bs[(kk+3)*128 + tx*4];
    #pragma unroll
    for(int j=0;j<8;j++){
      float4 a = *(float4*)&As[(ty*8+j)*68 + kk];
      acc2[j][0] += a.x*b0.x; acc2[j][1] += a.x*b0.y;
      acc2[j][2] += a.x*b0.z; acc2[j][3] += a.x*b0.w;
      acc2[j][0] += a.y*b1.x; acc2[j][1] += a.y*b1.y;
      acc2[j][2] += a.y*b1.z; acc2[j][3] += a.y*b1.w;
      acc2[j][0] += a.z*b2.x; acc2[j][1] += a.z*b2.y;
      acc2[j][2] += a.z*b2.z; acc2[j][3] += a.z*b2.w;
      acc2[j][0] += a.w*b3.x; acc2[j][1] += a.w*b3.y;
      acc2[j][2] += a.w*b3.z; acc2[j][3] += a.w*b3.w;
    }
  }
  float invn = invn_p[0];
  float bi[4], scv[4], bt[4], mn[4], pwv[4];
  #pragma unroll
  for(int i=0;i<4;i++){
    int c = tx*4+i;
    bi[i]  = bias[c];
    scv[i] = gamma[c] * (1.0f/sqrtf(var[c] + BNEPS));
    bt[i]  = beta[c];
    mn[i]  = mean[c];
    pwv[i] = pw[c];
  }
  #pragma unroll
  for(int j=0;j<8;j++){
    int row = r0 + ty*8 + j;
    float v0 = fmaxf((acc2[j][0]+bi[0]-mn[0])*scv[0]+bt[0], 0.f);
    float v1 = fmaxf((acc2[j][1]+bi[1]-mn[1])*scv[1]+bt[1], 0.f);
    float v2 = fmaxf((acc2[j][2]+bi[2]-mn[2])*scv[2]+bt[2], 0.f);
    float v3 = fmaxf((acc2[j][3]+bi[3]-mn[3])*scv[3]+bt[3], 0.f);
    float4 o; o.x=v0; o.y=v1; o.z=v2; o.w=v3;
    *(float4*)(hout + (size_t)row*HDIM + tx*4) = o;
    float p = v0*pwv[0]+v1*pwv[1]+v2*pwv[2]+v3*pwv[3];
    #pragma unroll
    for(int m=16;m>=1;m>>=1) p += __shfl_xor(p, m, 64);
    if(tx==0) score[row] = tanhf(p * invn);
  }
}

// ---- layers 1..5: h has 128 cols, W 128x128 staged in 32-k tiles ----
__global__ __launch_bounds__(256) void k_agemm(int n,
    const int* __restrict__ nlist, const int* __restrict__ rp,
    const long long* __restrict__ ec, const float* __restrict__ dinvz,
    const float* __restrict__ gsc, const float* __restrict__ h,
    const float* __restrict__ Wm, const float* __restrict__ bias,
    const float* __restrict__ gamma, const float* __restrict__ beta,
    const float* __restrict__ mean, const float* __restrict__ var,
    const float* __restrict__ pw, const float* __restrict__ invn_p,
    float* __restrict__ hout, float* __restrict__ score){
  __shared__ float As[64*132];    // 64 rows x 128 k, stride 132 (16B-aligned rows)
  __shared__ float Bs[32*128];
  int t = threadIdx.x;
  int wid = t >> 6, lane = t & 63;
  int half = lane >> 5, sl32 = lane & 31;
  int r0 = blockIdx.x * 64;
  int g0 = r0 / n, bnd = (g0+1)*n;
  // phase 1: half-wave record split, 2 rows in flight per wave over 16 rows
  for(int jj = wid; jj < 64; jj += 4){
    int row = r0 + jj;
    int g = (row >= bnd) ? g0+1 : g0;
    int d = nlist[row];
    int ld = d - g*NPG0;
    int e0 = rp[g*RPS+ld], e1 = rp[g*RPS+ld+1];
    float4 acc; acc.x=0.f; acc.y=0.f; acc.z=0.f; acc.w=0.f;
    for(int b=e0;b<e1;b+=64){
      int mm = e1-b; if(mm>64) mm=64;
      long long rec = (lane<mm) ? ec[(size_t)g*EG + b + lane] : 0;
      int   sl = (int)(rec & 0xffffffffLL);
      float cl = __int_as_float((int)(rec>>32)) * gsc[sl];
      long long pk = (((long long)__float_as_int(cl))<<32) | (unsigned)sl;
      int mr = (mm+15) & ~15;
      for(int j2=0;j2<mr;j2+=16){
        #pragma unroll
        for(int u=0;u<8;u++){
          long long p = __shfl(pk, j2 + 2*u + half, 64);
          float c = __int_as_float((int)(p>>32));
          if(c != 0.f){
            int s = (int)(p & 0xffffffffLL);
            float4 hv = *(const float4*)(h + (size_t)s*HDIM + 4*sl32);
            acc.x += c*hv.x; acc.y += c*hv.y; acc.z += c*hv.z; acc.w += c*hv.w;
          }
        }
      }
    }
    acc.x += __shfl_xor(acc.x, 32, 64); acc.y += __shfl_xor(acc.y, 32, 64);
    acc.z += __shfl_xor(acc.z, 32, 64); acc.w += __shfl_xor(acc.w, 32, 64);
    if(half==0){
      float dvd = dinvz[d], gsd = gsc[d];
      float4 hs = *(const float4*)(h + (size_t)d*HDIM + 4*sl32);
      float4 o;
      o.x = dvd*(acc.x + gsd*hs.x); o.y = dvd*(acc.y + gsd*hs.y);
      o.z = dvd*(acc.z + gsd*hs.z); o.w = dvd*(acc.w + gsd*hs.w);
      *(float4*)&As[jj*132 + 4*sl32] = o;
    }
  }
  __syncthreads();
  // phase 2: tiled GEMM, A resident
  int tx = t & 31, ty = t >> 5;
  float acc2[8][4];
  #pragma unroll
  for(int j=0;j<8;j++){
    #pragma unroll
    for(int i=0;i<4;i++) acc2[j][i]=0.f;
  }
  for(int k0=0;k0<128;k0+=32){
    #pragma unroll
    for(int p=0;p<4;p++){
      int idx = p*256 + t;
      int kk = idx >> 5, cq = idx & 31;
      *(float4*)&Bs[kk*128 + cq*4] = *(const float4*)(Wm + (size_t)(k0+kk)*128 + cq*4);
    }
    __syncthreads();
    #pragma unroll
    for(int kk=0;kk<32;kk+=4){
      float4 b0 = *(float4*)&Bs[(kk+0)*128 + tx*4];
      float4 b1 = *(float4*)&Bs[(kk+1)*128 + tx*4];
      float4 b2 = *(float4*)&Bs[(kk+2)*128 + tx*4];
      float4 b3 = *(float4*)&Bs[(kk+3)*128 + tx*4];
      #pragma unroll
      for(int j=0;j<8;j++){
        float4 a = *(float4*)&As[(ty*8+j)*132 + k0 + kk];
        acc2[j][0] += a.x*b0.x; acc2[j][1] += a.x*b0.y;
        acc2[j][2] += a.x*b0.z; acc2[j][3] += a.x*b0.w;
        acc2[j][0] += a.y*b1.x; acc2[j][1] += a.y*b1.y;
        acc2[j][2] += a.y*b1.z; acc2[j][3] += a.y*b1.w;
        acc2[j][0] += a.z*b2.x; acc2[j][1] += a.z*b2.y;
        acc2[j][2] += a.z*b2.z; acc2[j][3] += a.z*b2.w;
        acc2[j][0] += a.w*b3.x; acc2[j][1] += a.w*b3.y;
        acc2[j][2] += a.w*b3.z; acc2[j][3] += a.w*b3.w;
      }
    }
    __syncthreads();
  }
  // epilogue: bias + BN + ReLU, scatter raw rows to orig ids, score
  float invn = invn_p[0];
  float bi[4], scv[4], bt[4], mn[4], pwv[4];
  #pragma unroll
  for(int i=0;i<4;i++){
    int c = tx*4+i;
    bi[i]  = bias[c];
    scv[i] = gamma[c] * (1.0f/sqrtf(var[c] + BNEPS));
    bt[i]  = beta[c];
    mn[i]  = mean[c];
    pwv[i] = pw[c];
  }
  #pragma unroll
  for(int j=0;j<8;j++){
    int row = r0 + ty*8 + j;
    int orig = nlist[row];
    float v0 = fmaxf((acc2[j][0]+bi[0]-mn[0])*scv[0]+bt[0], 0.f);
    float v1 = fmaxf((acc2[j][1]+bi[1]-mn[1])*scv[1]+bt[1], 0.f);
    float v2 = fmaxf((acc2[j][2]+bi[2]-mn[2])*scv[2]+bt[2], 0.f);
    float v3 = fmaxf((acc2[j][3]+bi[3]-mn[3])*scv[3]+bt[3], 0.f);
    float4 o; o.x=v0; o.y=v1; o.z=v2; o.w=v3;
    *(float4*)(hout + (size_t)orig*HDIM + tx*4) = o;
    float p = v0*pwv[0]+v1*pwv[1]+v2*pwv[2]+v3*pwv[3];
    #pragma unroll
    for(int m=16;m>=1;m>>=1) p += __shfl_xor(p, m, 64);
    if(tx==0) score[row] = tanhf(p * invn);
  }
}

// ---------------- per-graph top-k: bitonic sort (score desc, idx asc) ----------------
__global__ __launch_bounds__(512) void k_topk(int n, int k, int P,
    const float* __restrict__ score, const int* __restrict__ curlist,
    float* __restrict__ vals, int* __restrict__ nextlist,
    float* __restrict__ dinvz, float* __restrict__ gsc){
  int g = blockIdx.x, t = threadIdx.x;
  __shared__ float s[1024];
  __shared__ int  id[1024];
  for(int i=t;i<P;i+=512){
    s[i]  = (i<n) ? score[g*n+i] : -FLT_MAX;
    id[i] = i;
  }
  __syncthreads();
  for(int k2=2;k2<=P;k2<<=1){
    for(int j=k2>>1;j>0;j>>=1){
      for(int i=t;i<P;i+=512){
        int ixj = i ^ j;
        if(ixj > i){
          bool desc = ((i & k2) == 0);
          float si = s[i], sx = s[ixj];
          int ii = id[i], ix = id[ixj];
          bool pre = (si > sx) || (si == sx && ii < ix);  // i precedes in desc order
          if(desc ? !pre : pre){ s[i]=sx; s[ixj]=si; id[i]=ix; id[ixj]=ii; }
        }
      }
      __syncthreads();
    }
  }
  for(int i=t;i<n;i+=512){
    int idx = id[i];
    int orig = curlist ? curlist[g*n+idx] : (g*NPG0 + idx);
    if(i<k){
      vals[g*k+i]=s[i]; nextlist[g*k+i]=orig;
    } else {
      dinvz[orig] = 0.f;               // node dies (alive sets nest)
      gsc[orig]   = 0.f;
    }
  }
}

// ---------------- pool partials + next-layer degree + gsc ----------------
__global__ __launch_bounds__(256) void k_gpd(int k, int do_deg,
    const float* __restrict__ hraw, const float* __restrict__ vals,
    const int* __restrict__ nextlist,
    float* __restrict__ sumst, float* __restrict__ maxst,
    const int* __restrict__ rp, const long long* __restrict__ ec,
    float* __restrict__ dinvz, float* __restrict__ gsc){
  int g = blockIdx.x & 63;
  int chunk = blockIdx.x >> 6;               // 0..POOL_NB-1
  int wid = threadIdx.x >> 6, lane = threadIdx.x & 63;
  int ww = chunk*4 + wid;                    // wave id within graph: 0..POOL_NB*4-1
  const int half = lane >> 5, sl32 = lane & 31;
  const int qw   = lane >> 4, sl16 = lane & 15;
  const int NH = POOL_NB*4*2;                // half-waves per graph
  float4 psum; psum.x=0.f; psum.y=0.f; psum.z=0.f; psum.w=0.f;
  float4 pmax; pmax.x=-FLT_MAX; pmax.y=-FLT_MAX; pmax.z=-FLT_MAX; pmax.w=-FLT_MAX;
  for(int j = ww*2 + half; j < k; j += NH){
    float v = vals[g*k+j];
    int d = nextlist[g*k+j];
    float4 hv = *(const float4*)(hraw + (size_t)d*HDIM + 4*sl32);
    float4 o; o.x=hv.x*v; o.y=hv.y*v; o.z=hv.z*v; o.w=hv.w*v;
    psum.x+=o.x; psum.y+=o.y; psum.z+=o.z; psum.w+=o.w;
    pmax.x=fmaxf(pmax.x,o.x); pmax.y=fmaxf(pmax.y,o.y);
    pmax.z=fmaxf(pmax.z,o.z); pmax.w=fmaxf(pmax.w,o.w);
  }
  if(do_deg){
    const int NQ = POOL_NB*4*4;              // quarter-waves per graph
    for(int j = ww*4 + qw; j < k; j += NQ){
      int d  = nextlist[g*k + j];
      int ld = d - g*NPG0;
      int e0 = rp[g*RPS+ld], e1 = rp[g*RPS+ld+1];
      float deg = 0.f;
      for(int b=e0+sl16; b<e1; b+=16){
        long long rec = ec[(size_t)g*EG + b];
        int s = (int)(rec & 0xffffffffLL);
        float w = __int_as_float((int)(rec>>32));
        if(dinvz[s] != 0.f) deg += w;
      }
      #pragma unroll
      for(int o=8;o>0;o>>=1) deg += __shfl_xor(deg, o, 64);  // within 16-lane group
      if(sl16==0){
        float dv = 1.0f / sqrtf(deg + 1.0f);
        dinvz[d] = dv;
        gsc[d] = dv * vals[g*k+j];
      }
    }
  }
  // cross-half reduce
  psum.x += __shfl_xor(psum.x, 32, 64); psum.y += __shfl_xor(psum.y, 32, 64);
  psum.z += __shfl_xor(psum.z, 32, 64); psum.w += __shfl_xor(psum.w, 32, 64);
  pmax.x = fmaxf(pmax.x, __shfl_xor(pmax.x, 32, 64));
  pmax.y = fmaxf(pmax.y, __shfl_xor(pmax.y, 32, 64));
  pmax.z = fmaxf(pmax.z, __shfl_xor(pmax.z, 32, 64));
  pmax.w = fmaxf(pmax.w, __shfl_xor(pmax.w, 32, 64));
  __shared__ float ss[4][128];
  __shared__ float sm[4][128];
  if(half==0){
    *(float4*)&ss[wid][4*sl32] = psum;
    *(float4*)&sm[wid][4*sl32] = pmax;
  }
  __syncthreads();
  int t = threadIdx.x;
  if(t < 128){
    float s = (ss[0][t]+ss[1][t]) + (ss[2][t]+ss[3][t]);
    float m = fmaxf(fmaxf(sm[0][t], sm[1][t]), fmaxf(sm[2][t], sm[3][t]));
    sumst[(size_t)(chunk*NGR + g)*HDIM + t] = s;
    maxst[(size_t)(chunk*NGR + g)*HDIM + t] = m;
  }
}

// ---------------- MLP head (folds 6 layers x POOL_NB chunk partials) ----------------
__global__ __launch_bounds__(512) void k_head(const float* __restrict__ sumstage,
    const float* __restrict__ maxstage,
    const float* __restrict__ d1w, const float* __restrict__ d1b,
    const float* __restrict__ d2w, const float* __restrict__ d2b, float* __restrict__ out){
  const float kinv[6] = {1.f/800.f, 1.f/640.f, 1.f/512.f, 1.f/410.f, 1.f/328.f, 1.f/263.f};
  int g = blockIdx.x, j = threadIdx.x;
  __shared__ float fl[256];
  __shared__ float hd[512];
  if(j < 128){
    float s = 0.f;
    #pragma unroll
    for(int l=0;l<6;l++){
      float ls = 0.f;
      for(int c=0;c<POOL_NB;c++)
        ls += sumstage[(size_t)((l*POOL_NB + c)*NGR + g)*HDIM + j];
      s += ls * kinv[l];
    }
    fl[j] = s;
  } else if(j < 256){
    int f = j - 128;
    float m = 0.f;
    #pragma unroll
    for(int l=0;l<6;l++){
      float lm = -FLT_MAX;
      for(int c=0;c<POOL_NB;c++)
        lm = fmaxf(lm, maxstage[(size_t)((l*POOL_NB + c)*NGR + g)*HDIM + f]);
      m += lm;
    }
    fl[j] = m;
  }
  __syncthreads();
  float acc = d1b[j];
  for(int i=0;i<256;i++) acc += fl[i]*d1w[i*512+j];
  hd[j] = fmaxf(acc, 0.f);
  __syncthreads();
  if(j < 10){
    float a = d2b[j];
    for(int i=0;i<512;i++) a += hd[i]*d2w[i*10+j];
    out[g*10+j] = a;
  }
}

extern "C" void kernel_launch(void* const* d_in, const int* in_sizes, int n_in,
                              void* d_out, int out_size, void* d_ws, size_t ws_size,
                              hipStream_t stream) {
  const float* x    = (const float*)d_in[0];
  const int* ei     = (const int*)d_in[1];
  const float* ew   = (const float*)d_in[3];
  const float* conv1w = (const float*)d_in[4];
  const float* convw  = (const float*)d_in[5];
  const float* convb  = (const float*)d_in[6];
  const float* bng    = (const float*)d_in[7];
  const float* bnb    = (const float*)d_in[8];
  const float* bnm    = (const float*)d_in[9];
  const float* bnv    = (const float*)d_in[10];
  const float* poolw  = (const float*)d_in[11];
  const float* d1w    = (const float*)d_in[12];
  const float* d1b    = (const float*)d_in[13];
  const float* d2w    = (const float*)d_in[14];
  const float* d2b    = (const float*)d_in[15];
  float* out = (float*)d_out;

  char* w = (char*)d_ws;
  float* horig = (float*)w; w += (size_t)64000*128*4;   // raw gemm outputs by ORIGINAL node id
  long long* ec = (long long*)w; w += (size_t)NE*8;     // static (w, src_orig), dst-bucketed
  int*   rp    = (int*)w;   w += (size_t)NGR*RPS*4;
  int*   pcnt  = (int*)w;   w += (size_t)256*NPG0*4;
  float* pdeg  = (float*)w; w += (size_t)256*NPG0*4;
  float* dinvz = (float*)w; w += (size_t)64000*4;       // 0 == node dead (alive indicator)
  float* gsc   = (float*)w; w += (size_t)64000*4;       // dinv_new * topk_val (0 == dead)
  float* score = (float*)w; w += (size_t)64000*4;
  float* vals  = (float*)w; w += (size_t)51200*4;
  int*   listA = (int*)w;   w += (size_t)51200*4;
  int*   listB = (int*)w;   w += (size_t)51200*4;
  float* invno = (float*)w; w += 64;
  float* sumstage = (float*)w; w += (size_t)6*POOL_NB*NGR*HDIM*4;
  float* maxstage = (float*)w; w += (size_t)6*POOL_NB*NGR*HDIM*4;

  k_invnorm<<<6,128,0,stream>>>(poolw, invno);

  const int ns[6]={1000,800,640,512,410,328};
  const int ks[6]={800,640,512,410,328,263};

  // ---- one-time CSR build (original ids), atomic-free count ----
  k_count0<<<256,256,0,stream>>>(ei+NE, ew, pcnt, pdeg);
  k_scan0<<<64,512,0,stream>>>(pcnt, pdeg, rp, dinvz, gsc);
  k_scatter0<<<64,1024,0,stream>>>(ei, ei+NE, ew, rp, ec);

  // ---- layer 0 (fused agg+gemm; input = x, 64 cols) ----
  k_agemm0<<<1000,256,0,stream>>>(rp, ec, dinvz, gsc, x, conv1w, convb, bng, bnb, bnm, bnv,
                                  poolw, invno, horig, score);
  k_topk<<<64,512,0,stream>>>(1000, 800, 1024, score, nullptr, vals, listA, dinvz, gsc);
  k_gpd<<<64*POOL_NB,256,0,stream>>>(800, 1, horig, vals, listA,
                                     sumstage, maxstage, rp, ec, dinvz, gsc);

  // ---- layers 1..5 (fused agg+gemm) ----
  int* cur = listA; int* nxt = listB;
  for(int i=1;i<6;i++){
    int n = ns[i], k = ks[i];
    k_agemm<<<n,256,0,stream>>>(n, cur, rp, ec, dinvz, gsc, horig,
                                convw+(size_t)(i-1)*128*128, convb+i*128, bng+i*128,
                                bnb+i*128, bnm+i*128, bnv+i*128, poolw+i*128, invno+i,
                                horig, score);
    int P = (n > 512) ? 1024 : 512;
    k_topk<<<64,512,0,stream>>>(n, k, P, score, cur, vals, nxt, dinvz, gsc);
    k_gpd<<<64*POOL_NB,256,0,stream>>>(k, (i<5)?1:0, horig, vals, nxt,
                                       sumstage + (size_t)i*POOL_NB*NGR*HDIM,
                                       maxstage + (size_t)i*POOL_NB*NGR*HDIM,
                                       rp, ec, dinvz, gsc);
    int* tmp = cur; cur = nxt; nxt = tmp;
  }

  k_head<<<64,512,0,stream>>>(sumstage, maxstage, d1w, d1b, d2w, d2b, out);
}

// Round 13
// 803.580 us; speedup vs baseline: 1.2466x; 1.2466x over previous
//
#include <hip/hip_runtime.h>
#include <float.h>
#include <math.h>

#define NGR 64        // graphs
#define NPG0 1000     // original nodes per graph
#define HDIM 128
#define EG 16000      // edges per graph
#define NE (NGR*EG)   // 1,024,000
#define RPS 1008      // rp row stride
#define BNEPS 1e-5f
#define POOL_NB 16

// ---------------- invnorm of pool_w rows (6 layers) ----------------
__global__ void k_invnorm(const float* __restrict__ pw, float* __restrict__ invnorm){
  int i = blockIdx.x;                  // layer
  int t = threadIdx.x;                 // 128 threads
  float v = pw[i*HDIM + t];
  float s = v*v;
  #pragma unroll
  for(int o=32;o>0;o>>=1) s += __shfl_down(s, o, 64);
  __shared__ float red[2];
  if((t & 63)==0) red[t>>6] = s;
  __syncthreads();
  if(t==0) invnorm[i] = 1.0f / sqrtf(red[0]+red[1]);
}

// ---------------- build phase: per-graph-chunk LDS count + weighted degree ----------------
__global__ __launch_bounds__(256) void k_count0(const int* __restrict__ dst,
    const float* __restrict__ we, int* __restrict__ pcnt, float* __restrict__ pdeg){
  int g = blockIdx.x >> 2, sub = blockIdx.x & 3, t = threadIdx.x;
  __shared__ int   cnt[NPG0];
  __shared__ float degl[NPG0];
  for(int i=t;i<NPG0;i+=256){ cnt[i]=0; degl[i]=0.f; }
  __syncthreads();
  int base = g*EG + sub*4000;
  for(int idx=t; idx<4000; idx+=256){
    int e = base + idx;
    int ld = dst[e] - g*NPG0;
    atomicAdd(&cnt[ld], 1);
    atomicAdd(&degl[ld], we[e]);
  }
  __syncthreads();
  int p = blockIdx.x * NPG0;
  for(int i=t;i<NPG0;i+=256){ pcnt[p+i] = cnt[i]; pdeg[p+i] = degl[i]; }
}

__global__ __launch_bounds__(512) void k_scan0(const int* __restrict__ pcnt,
    const float* __restrict__ pdeg, int* __restrict__ rp, float* __restrict__ dinvz,
    float* __restrict__ gsc){
  int g = blockIdx.x, t = threadIdx.x;
  __shared__ int sc[2][1024];
  for(int i=t;i<1024;i+=512){
    int c = 0;
    if(i<NPG0){
      c = pcnt[(g*4+0)*NPG0+i] + pcnt[(g*4+1)*NPG0+i]
        + pcnt[(g*4+2)*NPG0+i] + pcnt[(g*4+3)*NPG0+i];
      float dg = pdeg[(g*4+0)*NPG0+i] + pdeg[(g*4+1)*NPG0+i]
               + pdeg[(g*4+2)*NPG0+i] + pdeg[(g*4+3)*NPG0+i];
      float dv = 1.0f / sqrtf(dg + 1.0f);
      dinvz[g*NPG0+i] = dv;
      gsc[g*NPG0+i]   = dv;      // layer-0 feature scale: val == 1
    }
    sc[0][i] = c;
  }
  __syncthreads();
  int buf = 0;
  for(int d=1; d<1024; d<<=1){
    for(int i=t;i<1024;i+=512){
      int v = sc[buf][i];
      if(i>=d) v += sc[buf][i-d];
      sc[buf^1][i] = v;
    }
    __syncthreads();
    buf ^= 1;
  }
  for(int i=t;i<=NPG0;i+=512) rp[g*RPS+i] = (i==0) ? 0 : sc[buf][i-1];
}

// ---------------- scatter: per-graph LDS cursor ----------------
// ec record = (float w)<<32 | src_orig  (static for whole run)
__global__ __launch_bounds__(1024) void k_scatter0(const int* __restrict__ src,
    const int* __restrict__ dst, const float* __restrict__ we,
    const int* __restrict__ rp, long long* __restrict__ ec){
  int g = blockIdx.x, t = threadIdx.x;
  __shared__ int cur[NPG0];
  for(int i=t;i<NPG0;i+=1024) cur[i] = rp[g*RPS+i];
  __syncthreads();
  int base = g*EG;
  for(int idx=t; idx<EG; idx+=1024){
    int e = base + idx;
    int ld = dst[e] - g*NPG0;
    int pos = atomicAdd(&cur[ld], 1);
    ec[(size_t)base + pos] = (((long long)__float_as_int(we[e]))<<32) | (unsigned)src[e];
  }
}

// ================= FUSED aggregation + GEMM (XCD-swizzled) =================
// Grid = 64 graphs x ceil(n/64) chunks; g = blockIdx&63 so all chunks of graph g
// land on XCD g%8 -> per-XCD gather working set = 4MB horig slice (L2-resident).
// Phase 1 aggregates the block's A-tile rows into LDS; phase 2 runs the tiled GEMM.

// ---- layer 0: x has 64 cols, W 64x128 fully LDS-resident ----
__global__ __launch_bounds__(256) void k_agemm0(
    const int* __restrict__ rp, const long long* __restrict__ ec,
    const float* __restrict__ dinvz, const float* __restrict__ gsc,
    const float* __restrict__ x, const float* __restrict__ Wm,
    const float* __restrict__ bias, const float* __restrict__ gamma,
    const float* __restrict__ beta, const float* __restrict__ mean,
    const float* __restrict__ var, const float* __restrict__ pw,
    const float* __restrict__ invn_p, float* __restrict__ hout,
    float* __restrict__ score){
  __shared__ float As[64*68];     // 64 rows x 64 k, stride 68
  __shared__ float Bs[64*128];    // full W1
  const int n = 1000;
  int t = threadIdx.x;
  int wid = t >> 6, lane = t & 63;
  int qw = lane >> 4, sl16 = lane & 15;
  int g = blockIdx.x & 63;
  int lr0 = (blockIdx.x >> 6) * 64;      // local row base within graph
  // stage full W (overlaps phase-1 gathers; barrier below orders both)
  #pragma unroll
  for(int p=0;p<8;p++){
    int idx = p*256 + t;
    int kk = idx >> 5, cq = idx & 31;
    *(float4*)&Bs[kk*128 + cq*4] = *(const float4*)(Wm + (size_t)kk*128 + cq*4);
  }
  // phase 1: quarter-wave record split, 4 rows in flight per wave
  for(int jj = wid; jj < 64; jj += 4){
    int lr = lr0 + jj;
    if(lr < n){
      int d = g*n + lr;                  // layer 0: orig id == compact id
      int e0 = rp[g*RPS+lr], e1 = rp[g*RPS+lr+1];
      float4 acc; acc.x=0.f; acc.y=0.f; acc.z=0.f; acc.w=0.f;
      for(int b=e0;b<e1;b+=64){
        int mm = e1-b; if(mm>64) mm=64;
        long long rec = (lane<mm) ? ec[(size_t)g*EG + b + lane] : 0;
        int   sl = (int)(rec & 0xffffffffLL);
        float cl = __int_as_float((int)(rec>>32)) * gsc[sl];
        long long pk = (((long long)__float_as_int(cl))<<32) | (unsigned)sl;
        int mr = (mm+31) & ~31;
        for(int j2=0;j2<mr;j2+=32){
          #pragma unroll
          for(int u=0;u<8;u++){
            long long p = __shfl(pk, j2 + 4*u + qw, 64);
            float c = __int_as_float((int)(p>>32));
            if(c != 0.f){
              int s = (int)(p & 0xffffffffLL);
              float4 hv = *(const float4*)(x + (size_t)s*64 + 4*sl16);
              acc.x += c*hv.x; acc.y += c*hv.y; acc.z += c*hv.z; acc.w += c*hv.w;
            }
          }
        }
      }
      acc.x += __shfl_xor(acc.x, 16, 64); acc.y += __shfl_xor(acc.y, 16, 64);
      acc.z += __shfl_xor(acc.z, 16, 64); acc.w += __shfl_xor(acc.w, 16, 64);
      acc.x += __shfl_xor(acc.x, 32, 64); acc.y += __shfl_xor(acc.y, 32, 64);
      acc.z += __shfl_xor(acc.z, 32, 64); acc.w += __shfl_xor(acc.w, 32, 64);
      if(qw==0){
        float dvd = dinvz[d], gsd = gsc[d];
        float4 hs = *(const float4*)(x + (size_t)d*64 + 4*sl16);
        float4 o;
        o.x = dvd*(acc.x + gsd*hs.x); o.y = dvd*(acc.y + gsd*hs.y);
        o.z = dvd*(acc.z + gsd*hs.z); o.w = dvd*(acc.w + gsd*hs.w);
        *(float4*)&As[jj*68 + 4*sl16] = o;
      }
    }
  }
  __syncthreads();
  // phase 2: barrier-free GEMM (A and W resident)
  int tx = t & 31, ty = t >> 5;
  float acc2[8][4];
  #pragma unroll
  for(int j=0;j<8;j++){
    #pragma unroll
    for(int i=0;i<4;i++) acc2[j][i]=0.f;
  }
  #pragma unroll 4
  for(int kk=0;kk<64;kk+=4){
    float4 b0 = *(float4*)&Bs[(kk+0)*128 + tx*4];
    float4 b1 = *(float4*)&Bs[(kk+1)*128 + tx*4];
    float4 b2 = *(float4*)&Bs[(kk+2)*128 + tx*4];
    float4 b3 = *(float4*)&Bs[(kk+3)*128 + tx*4];
    #pragma unroll
    for(int j=0;j<8;j++){
      float4 a = *(float4*)&As[(ty*8+j)*68 + kk];
      acc2[j][0] += a.x*b0.x; acc2[j][1] += a.x*b0.y;
      acc2[j][2] += a.x*b0.z; acc2[j][3] += a.x*b0.w;
      acc2[j][0] += a.y*b1.x; acc2[j][1] += a.y*b1.y;
      acc2[j][2] += a.y*b1.z; acc2[j][3] += a.y*b1.w;
      acc2[j][0] += a.z*b2.x; acc2[j][1] += a.z*b2.y;
      acc2[j][2] += a.z*b2.z; acc2[j][3] += a.z*b2.w;
      acc2[j][0] += a.w*b3.x; acc2[j][1] += a.w*b3.y;
      acc2[j][2] += a.w*b3.z; acc2[j][3] += a.w*b3.w;
    }
  }
  float invn = invn_p[0];
  float bi[4], scv[4], bt[4], mn[4], pwv[4];
  #pragma unroll
  for(int i=0;i<4;i++){
    int c = tx*4+i;
    bi[i]  = bias[c];
    scv[i] = gamma[c] * (1.0f/sqrtf(var[c] + BNEPS));
    bt[i]  = beta[c];
    mn[i]  = mean[c];
    pwv[i] = pw[c];
  }
  #pragma unroll
  for(int j=0;j<8;j++){
    int lr = lr0 + ty*8 + j;
    if(lr < n){
      int row = g*n + lr;
      float v0 = fmaxf((acc2[j][0]+bi[0]-mn[0])*scv[0]+bt[0], 0.f);
      float v1 = fmaxf((acc2[j][1]+bi[1]-mn[1])*scv[1]+bt[1], 0.f);
      float v2 = fmaxf((acc2[j][2]+bi[2]-mn[2])*scv[2]+bt[2], 0.f);
      float v3 = fmaxf((acc2[j][3]+bi[3]-mn[3])*scv[3]+bt[3], 0.f);
      float4 o; o.x=v0; o.y=v1; o.z=v2; o.w=v3;
      *(float4*)(hout + (size_t)row*HDIM + tx*4) = o;
      float p = v0*pwv[0]+v1*pwv[1]+v2*pwv[2]+v3*pwv[3];
      #pragma unroll
      for(int m=16;m>=1;m>>=1) p += __shfl_xor(p, m, 64);
      if(tx==0) score[row] = tanhf(p * invn);
    }
  }
}

// ---- layers 1..5: h has 128 cols, W 128x128 staged in 32-k tiles ----
__global__ __launch_bounds__(256) void k_agemm(int n,
    const int* __restrict__ nlist, const int* __restrict__ rp,
    const long long* __restrict__ ec, const float* __restrict__ dinvz,
    const float* __restrict__ gsc, const float* __restrict__ h,
    const float* __restrict__ Wm, const float* __restrict__ bias,
    const float* __restrict__ gamma, const float* __restrict__ beta,
    const float* __restrict__ mean, const float* __restrict__ var,
    const float* __restrict__ pw, const float* __restrict__ invn_p,
    float* __restrict__ hout, float* __restrict__ score){
  __shared__ float As[64*132];    // 64 rows x 128 k, stride 132
  __shared__ float Bs[32*128];
  int t = threadIdx.x;
  int wid = t >> 6, lane = t & 63;
  int half = lane >> 5, sl32 = lane & 31;
  int g = blockIdx.x & 63;
  int lr0 = (blockIdx.x >> 6) * 64;
  // phase 1: half-wave record split, 2 rows in flight per wave
  for(int jj = wid; jj < 64; jj += 4){
    int lr = lr0 + jj;
    if(lr < n){
      int row = g*n + lr;
      int d = nlist[row];
      int ld = d - g*NPG0;
      int e0 = rp[g*RPS+ld], e1 = rp[g*RPS+ld+1];
      float4 acc; acc.x=0.f; acc.y=0.f; acc.z=0.f; acc.w=0.f;
      for(int b=e0;b<e1;b+=64){
        int mm = e1-b; if(mm>64) mm=64;
        long long rec = (lane<mm) ? ec[(size_t)g*EG + b + lane] : 0;
        int   sl = (int)(rec & 0xffffffffLL);
        float cl = __int_as_float((int)(rec>>32)) * gsc[sl];
        long long pk = (((long long)__float_as_int(cl))<<32) | (unsigned)sl;
        int mr = (mm+15) & ~15;
        for(int j2=0;j2<mr;j2+=16){
          #pragma unroll
          for(int u=0;u<8;u++){
            long long p = __shfl(pk, j2 + 2*u + half, 64);
            float c = __int_as_float((int)(p>>32));
            if(c != 0.f){
              int s = (int)(p & 0xffffffffLL);
              float4 hv = *(const float4*)(h + (size_t)s*HDIM + 4*sl32);
              acc.x += c*hv.x; acc.y += c*hv.y; acc.z += c*hv.z; acc.w += c*hv.w;
            }
          }
        }
      }
      acc.x += __shfl_xor(acc.x, 32, 64); acc.y += __shfl_xor(acc.y, 32, 64);
      acc.z += __shfl_xor(acc.z, 32, 64); acc.w += __shfl_xor(acc.w, 32, 64);
      if(half==0){
        float dvd = dinvz[d], gsd = gsc[d];
        float4 hs = *(const float4*)(h + (size_t)d*HDIM + 4*sl32);
        float4 o;
        o.x = dvd*(acc.x + gsd*hs.x); o.y = dvd*(acc.y + gsd*hs.y);
        o.z = dvd*(acc.z + gsd*hs.z); o.w = dvd*(acc.w + gsd*hs.w);
        *(float4*)&As[jj*132 + 4*sl32] = o;
      }
    }
  }
  __syncthreads();
  // phase 2: tiled GEMM, A resident
  int tx = t & 31, ty = t >> 5;
  float acc2[8][4];
  #pragma unroll
  for(int j=0;j<8;j++){
    #pragma unroll
    for(int i=0;i<4;i++) acc2[j][i]=0.f;
  }
  for(int k0=0;k0<128;k0+=32){
    #pragma unroll
    for(int p=0;p<4;p++){
      int idx = p*256 + t;
      int kk = idx >> 5, cq = idx & 31;
      *(float4*)&Bs[kk*128 + cq*4] = *(const float4*)(Wm + (size_t)(k0+kk)*128 + cq*4);
    }
    __syncthreads();
    #pragma unroll
    for(int kk=0;kk<32;kk+=4){
      float4 b0 = *(float4*)&Bs[(kk+0)*128 + tx*4];
      float4 b1 = *(float4*)&Bs[(kk+1)*128 + tx*4];
      float4 b2 = *(float4*)&Bs[(kk+2)*128 + tx*4];
      float4 b3 = *(float4*)&Bs[(kk+3)*128 + tx*4];
      #pragma unroll
      for(int j=0;j<8;j++){
        float4 a = *(float4*)&As[(ty*8+j)*132 + k0 + kk];
        acc2[j][0] += a.x*b0.x; acc2[j][1] += a.x*b0.y;
        acc2[j][2] += a.x*b0.z; acc2[j][3] += a.x*b0.w;
        acc2[j][0] += a.y*b1.x; acc2[j][1] += a.y*b1.y;
        acc2[j][2] += a.y*b1.z; acc2[j][3] += a.y*b1.w;
        acc2[j][0] += a.z*b2.x; acc2[j][1] += a.z*b2.y;
        acc2[j][2] += a.z*b2.z; acc2[j][3] += a.z*b2.w;
        acc2[j][0] += a.w*b3.x; acc2[j][1] += a.w*b3.y;
        acc2[j][2] += a.w*b3.z; acc2[j][3] += a.w*b3.w;
      }
    }
    __syncthreads();
  }
  // epilogue: bias + BN + ReLU, scatter raw rows to orig ids, score
  float invn = invn_p[0];
  float bi[4], scv[4], bt[4], mn[4], pwv[4];
  #pragma unroll
  for(int i=0;i<4;i++){
    int c = tx*4+i;
    bi[i]  = bias[c];
    scv[i] = gamma[c] * (1.0f/sqrtf(var[c] + BNEPS));
    bt[i]  = beta[c];
    mn[i]  = mean[c];
    pwv[i] = pw[c];
  }
  #pragma unroll
  for(int j=0;j<8;j++){
    int lr = lr0 + ty*8 + j;
    if(lr < n){
      int row = g*n + lr;
      int orig = nlist[row];
      float v0 = fmaxf((acc2[j][0]+bi[0]-mn[0])*scv[0]+bt[0], 0.f);
      float v1 = fmaxf((acc2[j][1]+bi[1]-mn[1])*scv[1]+bt[1], 0.f);
      float v2 = fmaxf((acc2[j][2]+bi[2]-mn[2])*scv[2]+bt[2], 0.f);
      float v3 = fmaxf((acc2[j][3]+bi[3]-mn[3])*scv[3]+bt[3], 0.f);
      float4 o; o.x=v0; o.y=v1; o.z=v2; o.w=v3;
      *(float4*)(hout + (size_t)orig*HDIM + tx*4) = o;
      float p = v0*pwv[0]+v1*pwv[1]+v2*pwv[2]+v3*pwv[3];
      #pragma unroll
      for(int m=16;m>=1;m>>=1) p += __shfl_xor(p, m, 64);
      if(tx==0) score[row] = tanhf(p * invn);
    }
  }
}

// ---------------- per-graph top-k: bitonic sort (score desc, idx asc) ----------------
__global__ __launch_bounds__(512) void k_topk(int n, int k, int P,
    const float* __restrict__ score, const int* __restrict__ curlist,
    float* __restrict__ vals, int* __restrict__ nextlist,
    float* __restrict__ dinvz, float* __restrict__ gsc){
  int g = blockIdx.x, t = threadIdx.x;
  __shared__ float s[1024];
  __shared__ int  id[1024];
  for(int i=t;i<P;i+=512){
    s[i]  = (i<n) ? score[g*n+i] : -FLT_MAX;
    id[i] = i;
  }
  __syncthreads();
  for(int k2=2;k2<=P;k2<<=1){
    for(int j=k2>>1;j>0;j>>=1){
      for(int i=t;i<P;i+=512){
        int ixj = i ^ j;
        if(ixj > i){
          bool desc = ((i & k2) == 0);
          float si = s[i], sx = s[ixj];
          int ii = id[i], ix = id[ixj];
          bool pre = (si > sx) || (si == sx && ii < ix);  // i precedes in desc order
          if(desc ? !pre : pre){ s[i]=sx; s[ixj]=si; id[i]=ix; id[ixj]=ii; }
        }
      }
      __syncthreads();
    }
  }
  for(int i=t;i<n;i+=512){
    int idx = id[i];
    int orig = curlist ? curlist[g*n+idx] : (g*NPG0 + idx);
    if(i<k){
      vals[g*k+i]=s[i]; nextlist[g*k+i]=orig;
    } else {
      dinvz[orig] = 0.f;               // node dies (alive sets nest)
      gsc[orig]   = 0.f;
    }
  }
}

// ---------------- pool partials + next-layer degree + gsc ----------------
__global__ __launch_bounds__(256) void k_gpd(int k, int do_deg,
    const float* __restrict__ hraw, const float* __restrict__ vals,
    const int* __restrict__ nextlist,
    float* __restrict__ sumst, float* __restrict__ maxst,
    const int* __restrict__ rp, const long long* __restrict__ ec,
    float* __restrict__ dinvz, float* __restrict__ gsc){
  int g = blockIdx.x & 63;
  int chunk = blockIdx.x >> 6;               // 0..POOL_NB-1
  int wid = threadIdx.x >> 6, lane = threadIdx.x & 63;
  int ww = chunk*4 + wid;                    // wave id within graph: 0..POOL_NB*4-1
  const int half = lane >> 5, sl32 = lane & 31;
  const int qw   = lane >> 4, sl16 = lane & 15;
  const int NH = POOL_NB*4*2;                // half-waves per graph
  float4 psum; psum.x=0.f; psum.y=0.f; psum.z=0.f; psum.w=0.f;
  float4 pmax; pmax.x=-FLT_MAX; pmax.y=-FLT_MAX; pmax.z=-FLT_MAX; pmax.w=-FLT_MAX;
  for(int j = ww*2 + half; j < k; j += NH){
    float v = vals[g*k+j];
    int d = nextlist[g*k+j];
    float4 hv = *(const float4*)(hraw + (size_t)d*HDIM + 4*sl32);
    float4 o; o.x=hv.x*v; o.y=hv.y*v; o.z=hv.z*v; o.w=hv.w*v;
    psum.x+=o.x; psum.y+=o.y; psum.z+=o.z; psum.w+=o.w;
    pmax.x=fmaxf(pmax.x,o.x); pmax.y=fmaxf(pmax.y,o.y);
    pmax.z=fmaxf(pmax.z,o.z); pmax.w=fmaxf(pmax.w,o.w);
  }
  if(do_deg){
    const int NQ = POOL_NB*4*4;              // quarter-waves per graph
    for(int j = ww*4 + qw; j < k; j += NQ){
      int d  = nextlist[g*k + j];
      int ld = d - g*NPG0;
      int e0 = rp[g*RPS+ld], e1 = rp[g*RPS+ld+1];
      float deg = 0.f;
      for(int b=e0+sl16; b<e1; b+=16){
        long long rec = ec[(size_t)g*EG + b];
        int s = (int)(rec & 0xffffffffLL);
        float w = __int_as_float((int)(rec>>32));
        if(dinvz[s] != 0.f) deg += w;
      }
      #pragma unroll
      for(int o=8;o>0;o>>=1) deg += __shfl_xor(deg, o, 64);  // within 16-lane group
      if(sl16==0){
        float dv = 1.0f / sqrtf(deg + 1.0f);
        dinvz[d] = dv;
        gsc[d] = dv * vals[g*k+j];
      }
    }
  }
  // cross-half reduce
  psum.x += __shfl_xor(psum.x, 32, 64); psum.y += __shfl_xor(psum.y, 32, 64);
  psum.z += __shfl_xor(psum.z, 32, 64); psum.w += __shfl_xor(psum.w, 32, 64);
  pmax.x = fmaxf(pmax.x, __shfl_xor(pmax.x, 32, 64));
  pmax.y = fmaxf(pmax.y, __shfl_xor(pmax.y, 32, 64));
  pmax.z = fmaxf(pmax.z, __shfl_xor(pmax.z, 32, 64));
  pmax.w = fmaxf(pmax.w, __shfl_xor(pmax.w, 32, 64));
  __shared__ float ss[4][128];
  __shared__ float sm[4][128];
  if(half==0){
    *(float4*)&ss[wid][4*sl32] = psum;
    *(float4*)&sm[wid][4*sl32] = pmax;
  }
  __syncthreads();
  int t = threadIdx.x;
  if(t < 128){
    float s = (ss[0][t]+ss[1][t]) + (ss[2][t]+ss[3][t]);
    float m = fmaxf(fmaxf(sm[0][t], sm[1][t]), fmaxf(sm[2][t], sm[3][t]));
    sumst[(size_t)(chunk*NGR + g)*HDIM + t] = s;
    maxst[(size_t)(chunk*NGR + g)*HDIM + t] = m;
  }
}

// ---------------- MLP head (folds 6 layers x POOL_NB chunk partials) ----------------
__global__ __launch_bounds__(512) void k_head(const float* __restrict__ sumstage,
    const float* __restrict__ maxstage,
    const float* __restrict__ d1w, const float* __restrict__ d1b,
    const float* __restrict__ d2w, const float* __restrict__ d2b, float* __restrict__ out){
  const float kinv[6] = {1.f/800.f, 1.f/640.f, 1.f/512.f, 1.f/410.f, 1.f/328.f, 1.f/263.f};
  int g = blockIdx.x, j = threadIdx.x;
  __shared__ float fl[256];
  __shared__ float hd[512];
  if(j < 128){
    float s = 0.f;
    #pragma unroll
    for(int l=0;l<6;l++){
      float ls = 0.f;
      for(int c=0;c<POOL_NB;c++)
        ls += sumstage[(size_t)((l*POOL_NB + c)*NGR + g)*HDIM + j];
      s += ls * kinv[l];
    }
    fl[j] = s;
  } else if(j < 256){
    int f = j - 128;
    float m = 0.f;
    #pragma unroll
    for(int l=0;l<6;l++){
      float lm = -FLT_MAX;
      for(int c=0;c<POOL_NB;c++)
        lm = fmaxf(lm, maxstage[(size_t)((l*POOL_NB + c)*NGR + g)*HDIM + f]);
      m += lm;
    }
    fl[j] = m;
  }
  __syncthreads();
  float acc = d1b[j];
  for(int i=0;i<256;i++) acc += fl[i]*d1w[i*512+j];
  hd[j] = fmaxf(acc, 0.f);
  __syncthreads();
  if(j < 10){
    float a = d2b[j];
    for(int i=0;i<512;i++) a += hd[i]*d2w[i*10+j];
    out[g*10+j] = a;
  }
}

extern "C" void kernel_launch(void* const* d_in, const int* in_sizes, int n_in,
                              void* d_out, int out_size, void* d_ws, size_t ws_size,
                              hipStream_t stream) {
  const float* x    = (const float*)d_in[0];
  const int* ei     = (const int*)d_in[1];
  const float* ew   = (const float*)d_in[3];
  const float* conv1w = (const float*)d_in[4];
  const float* convw  = (const float*)d_in[5];
  const float* convb  = (const float*)d_in[6];
  const float* bng    = (const float*)d_in[7];
  const float* bnb    = (const float*)d_in[8];
  const float* bnm    = (const float*)d_in[9];
  const float* bnv    = (const float*)d_in[10];
  const float* poolw  = (const float*)d_in[11];
  const float* d1w    = (const float*)d_in[12];
  const float* d1b    = (const float*)d_in[13];
  const float* d2w    = (const float*)d_in[14];
  const float* d2b    = (const float*)d_in[15];
  float* out = (float*)d_out;

  char* w = (char*)d_ws;
  float* horig = (float*)w; w += (size_t)64000*128*4;   // raw gemm outputs by ORIGINAL node id
  long long* ec = (long long*)w; w += (size_t)NE*8;     // static (w, src_orig), dst-bucketed
  int*   rp    = (int*)w;   w += (size_t)NGR*RPS*4;
  int*   pcnt  = (int*)w;   w += (size_t)256*NPG0*4;
  float* pdeg  = (float*)w; w += (size_t)256*NPG0*4;
  float* dinvz = (float*)w; w += (size_t)64000*4;       // 0 == node dead (alive indicator)
  float* gsc   = (float*)w; w += (size_t)64000*4;       // dinv_new * topk_val (0 == dead)
  float* score = (float*)w; w += (size_t)64000*4;
  float* vals  = (float*)w; w += (size_t)51200*4;
  int*   listA = (int*)w;   w += (size_t)51200*4;
  int*   listB = (int*)w;   w += (size_t)51200*4;
  float* invno = (float*)w; w += 64;
  float* sumstage = (float*)w; w += (size_t)6*POOL_NB*NGR*HDIM*4;
  float* maxstage = (float*)w; w += (size_t)6*POOL_NB*NGR*HDIM*4;

  k_invnorm<<<6,128,0,stream>>>(poolw, invno);

  const int ns[6]={1000,800,640,512,410,328};
  const int ks[6]={800,640,512,410,328,263};

  // ---- one-time CSR build (original ids), atomic-free count ----
  k_count0<<<256,256,0,stream>>>(ei+NE, ew, pcnt, pdeg);
  k_scan0<<<64,512,0,stream>>>(pcnt, pdeg, rp, dinvz, gsc);
  k_scatter0<<<64,1024,0,stream>>>(ei, ei+NE, ew, rp, ec);

  // ---- layer 0 (fused agg+gemm; input = x, 64 cols) ----
  k_agemm0<<<64*16,256,0,stream>>>(rp, ec, dinvz, gsc, x, conv1w, convb, bng, bnb, bnm, bnv,
                                   poolw, invno, horig, score);
  k_topk<<<64,512,0,stream>>>(1000, 800, 1024, score, nullptr, vals, listA, dinvz, gsc);
  k_gpd<<<64*POOL_NB,256,0,stream>>>(800, 1, horig, vals, listA,
                                     sumstage, maxstage, rp, ec, dinvz, gsc);

  // ---- layers 1..5 (fused agg+gemm, XCD-swizzled) ----
  int* cur = listA; int* nxt = listB;
  for(int i=1;i<6;i++){
    int n = ns[i], k = ks[i];
    int cpg = (n + 63) / 64;
    k_agemm<<<64*cpg,256,0,stream>>>(n, cur, rp, ec, dinvz, gsc, horig,
                                     convw+(size_t)(i-1)*128*128, convb+i*128, bng+i*128,
                                     bnb+i*128, bnm+i*128, bnv+i*128, poolw+i*128, invno+i,
                                     horig, score);
    int P = (n > 512) ? 1024 : 512;
    k_topk<<<64,512,0,stream>>>(n, k, P, score, cur, vals, nxt, dinvz, gsc);
    k_gpd<<<64*POOL_NB,256,0,stream>>>(k, (i<5)?1:0, horig, vals, nxt,
                                       sumstage + (size_t)i*POOL_NB*NGR*HDIM,
                                       maxstage + (size_t)i*POOL_NB*NGR*HDIM,
                                       rp, ec, dinvz, gsc);
    int* tmp = cur; cur = nxt; nxt = tmp;
  }

  k_head<<<64,512,0,stream>>>(sumstage, maxstage, d1w, d1b, d2w, d2b, out);
}

// Round 14
// 613.216 us; speedup vs baseline: 1.6336x; 1.3104x over previous
//
#include <hip/hip_runtime.h>
#include <float.h>
#include <math.h>

#define NGR 64        // graphs
#define NPG0 1000     // original nodes per graph
#define HDIM 128
#define EG 16000      // edges per graph
#define NE (NGR*EG)   // 1,024,000
#define RPS 1008      // rp row stride
#define BNEPS 1e-5f
#define POOL_NB 16

// ---------------- invnorm of pool_w rows (6 layers) ----------------
__global__ void k_invnorm(const float* __restrict__ pw, float* __restrict__ invnorm){
  int i = blockIdx.x;                  // layer
  int t = threadIdx.x;                 // 128 threads
  float v = pw[i*HDIM + t];
  float s = v*v;
  #pragma unroll
  for(int o=32;o>0;o>>=1) s += __shfl_down(s, o, 64);
  __shared__ float red[2];
  if((t & 63)==0) red[t>>6] = s;
  __syncthreads();
  if(t==0) invnorm[i] = 1.0f / sqrtf(red[0]+red[1]);
}

// ---------------- build phase: per-graph-chunk LDS count + weighted degree ----------------
__global__ __launch_bounds__(256) void k_count0(const int* __restrict__ dst,
    const float* __restrict__ we, int* __restrict__ pcnt, float* __restrict__ pdeg){
  int g = blockIdx.x >> 2, sub = blockIdx.x & 3, t = threadIdx.x;
  __shared__ int   cnt[NPG0];
  __shared__ float degl[NPG0];
  for(int i=t;i<NPG0;i+=256){ cnt[i]=0; degl[i]=0.f; }
  __syncthreads();
  int base = g*EG + sub*4000;
  for(int idx=t; idx<4000; idx+=256){
    int e = base + idx;
    int ld = dst[e] - g*NPG0;
    atomicAdd(&cnt[ld], 1);
    atomicAdd(&degl[ld], we[e]);
  }
  __syncthreads();
  int p = blockIdx.x * NPG0;
  for(int i=t;i<NPG0;i+=256){ pcnt[p+i] = cnt[i]; pdeg[p+i] = degl[i]; }
}

// ---------------- fused scan + scatter: block g owns graph g ----------------
// Sums the 4 count/deg partials, writes dinvz/gsc, exclusive-scans counts into rp,
// then scatters edge records via an LDS cursor seeded from the scan (no rp reload,
// no extra dispatch). ec record = (float w)<<32 | src_orig (static for whole run).
__global__ __launch_bounds__(1024) void k_build(const int* __restrict__ pcnt,
    const float* __restrict__ pdeg, const int* __restrict__ src,
    const int* __restrict__ dst, const float* __restrict__ we,
    int* __restrict__ rp, float* __restrict__ dinvz, float* __restrict__ gsc,
    long long* __restrict__ ec){
  int g = blockIdx.x, t = threadIdx.x;
  __shared__ int sc[2][1024];
  __shared__ int cur[NPG0];
  int c = 0;
  if(t < NPG0){
    c = pcnt[(g*4+0)*NPG0+t] + pcnt[(g*4+1)*NPG0+t]
      + pcnt[(g*4+2)*NPG0+t] + pcnt[(g*4+3)*NPG0+t];
    float dg = pdeg[(g*4+0)*NPG0+t] + pdeg[(g*4+1)*NPG0+t]
             + pdeg[(g*4+2)*NPG0+t] + pdeg[(g*4+3)*NPG0+t];
    float dv = 1.0f / sqrtf(dg + 1.0f);
    dinvz[g*NPG0+t] = dv;
    gsc[g*NPG0+t]   = dv;        // layer-0 feature scale: val == 1
  }
  sc[0][t] = c;
  __syncthreads();
  int buf = 0;
  for(int d=1; d<1024; d<<=1){
    int v = sc[buf][t];
    if(t>=d) v += sc[buf][t-d];
    sc[buf^1][t] = v;
    __syncthreads();
    buf ^= 1;
  }
  if(t<=NPG0) rp[g*RPS+t] = (t==0) ? 0 : sc[buf][t-1];
  if(t<NPG0)  cur[t]      = (t==0) ? 0 : sc[buf][t-1];
  __syncthreads();
  int base = g*EG;
  for(int idx=t; idx<EG; idx+=1024){
    int e = base + idx;
    int ld = dst[e] - g*NPG0;
    int pos = atomicAdd(&cur[ld], 1);
    ec[(size_t)base + pos] = (((long long)__float_as_int(we[e]))<<32) | (unsigned)src[e];
  }
}

// ---------------- aggregation over original-id buckets ----------------
// agg[compact dst row] = dvd * ( sum_e w*gsc[src]*raw[src] + gsc[d]*raw[d] )
template<int L0>
__global__ __launch_bounds__(256) void k_agg(int n, const int* __restrict__ nlist,
    const int* __restrict__ rp, const long long* __restrict__ ec,
    const float* __restrict__ dinvz, const float* __restrict__ gsc,
    const float* __restrict__ h, float* __restrict__ agg){
  int g = blockIdx.x & 63;            // graph-major: XCD locality
  int chunk = blockIdx.x >> 6;
  int wid = threadIdx.x >> 6, lane = threadIdx.x & 63;
  const int wpg = (gridDim.x >> 6) * 4;
  const int half = lane >> 5, sl32 = lane & 31;   // 128-col split
  const int qw   = lane >> 4, sl16 = lane & 15;   // 64-col split
  for(int j = chunk*4 + wid; j < n; j += wpg){
    int cg = g*n + j;                               // compact row
    int d  = L0 ? (g*NPG0 + j) : nlist[cg];         // original id
    int ld = d - g*NPG0;
    int e0 = rp[g*RPS+ld], e1 = rp[g*RPS+ld+1];
    float dvd = dinvz[d];
    float gsd = gsc[d];
    float4 acc; acc.x=0.f; acc.y=0.f; acc.z=0.f; acc.w=0.f;
    for(int b=e0;b<e1;b+=64){
      int mm = e1-b; if(mm>64) mm=64;
      long long rec = (lane<mm) ? ec[(size_t)g*EG + b + lane] : 0;
      int   sl = (int)(rec & 0xffffffffLL);
      float cl = __int_as_float((int)(rec>>32)) * gsc[sl];
      long long pk = (((long long)__float_as_int(cl))<<32) | (unsigned)sl;
      if(L0){
        int mr = (mm+31) & ~31;
        for(int jj=0;jj<mr;jj+=32){
          #pragma unroll
          for(int u=0;u<8;u++){
            long long p = __shfl(pk, jj + 4*u + qw, 64);
            float c = __int_as_float((int)(p>>32));
            if(c != 0.f){
              int s = (int)(p & 0xffffffffLL);
              float4 hv = *(const float4*)(h + (size_t)s*64 + 4*sl16);
              acc.x += c*hv.x; acc.y += c*hv.y; acc.z += c*hv.z; acc.w += c*hv.w;
            }
          }
        }
      } else {
        int mr = (mm+15) & ~15;
        for(int jj=0;jj<mr;jj+=16){
          #pragma unroll
          for(int u=0;u<8;u++){
            long long p = __shfl(pk, jj + 2*u + half, 64);
            float c = __int_as_float((int)(p>>32));
            if(c != 0.f){
              int s = (int)(p & 0xffffffffLL);
              float4 hv = *(const float4*)(h + (size_t)s*HDIM + 4*sl32);
              acc.x += c*hv.x; acc.y += c*hv.y; acc.z += c*hv.z; acc.w += c*hv.w;
            }
          }
        }
      }
    }
    if(L0){
      acc.x += __shfl_xor(acc.x, 16, 64); acc.y += __shfl_xor(acc.y, 16, 64);
      acc.z += __shfl_xor(acc.z, 16, 64); acc.w += __shfl_xor(acc.w, 16, 64);
      acc.x += __shfl_xor(acc.x, 32, 64); acc.y += __shfl_xor(acc.y, 32, 64);
      acc.z += __shfl_xor(acc.z, 32, 64); acc.w += __shfl_xor(acc.w, 32, 64);
      if(qw==0){
        float4 hs = *(const float4*)(h + (size_t)d*64 + 4*sl16);
        float4 o;
        o.x = dvd*(acc.x + gsd*hs.x); o.y = dvd*(acc.y + gsd*hs.y);
        o.z = dvd*(acc.z + gsd*hs.z); o.w = dvd*(acc.w + gsd*hs.w);
        *(float4*)(agg + (size_t)cg*64 + 4*sl16) = o;
      }
    } else {
      acc.x += __shfl_xor(acc.x, 32, 64); acc.y += __shfl_xor(acc.y, 32, 64);
      acc.z += __shfl_xor(acc.z, 32, 64); acc.w += __shfl_xor(acc.w, 32, 64);
      if(half==0){
        float4 hs = *(const float4*)(h + (size_t)d*HDIM + 4*sl32);
        float4 o;
        o.x = dvd*(acc.x + gsd*hs.x); o.y = dvd*(acc.y + gsd*hs.y);
        o.z = dvd*(acc.z + gsd*hs.z); o.w = dvd*(acc.w + gsd*hs.w);
        *(float4*)(agg + (size_t)cg*HDIM + 4*sl32) = o;
      }
    }
  }
}

// ---------------- fp32 GEMM (64 rows x 128 cols / block, BK=32) + bias + BN + ReLU + score ----
// Output rows scattered to orig-id order (hout[olist[row]]) so no later re-layout pass.
template<int KIN>
__global__ __launch_bounds__(256) void k_gemm(const float* __restrict__ Ain,
    const float* __restrict__ Wm, const float* __restrict__ bias,
    const float* __restrict__ gamma, const float* __restrict__ beta,
    const float* __restrict__ mean, const float* __restrict__ var,
    const float* __restrict__ pw, const float* __restrict__ invn_p,
    const int* __restrict__ olist, float* __restrict__ hout, float* __restrict__ score){
  __shared__ float As[64*40];    // row-major [row][k], stride 40 (16B-aligned rows)
  __shared__ float Bs[32*128];   // [k][col]
  int t = threadIdx.x;
  int tx = t & 31, ty = t >> 5;  // thread: rows ty*8..+7, cols tx*4..+3
  int r0 = blockIdx.x * 64;
  float acc[8][4];
  #pragma unroll
  for(int j=0;j<8;j++){
    #pragma unroll
    for(int i=0;i<4;i++) acc[j][i]=0.f;
  }
  for(int k0=0;k0<KIN;k0+=32){
    #pragma unroll
    for(int p=0;p<2;p++){              // stage A 64x32 via float4
      int idx = p*256 + t;             // 0..511
      int rr = idx >> 3, kq = idx & 7;
      float4 av = *(const float4*)(Ain + (size_t)(r0+rr)*KIN + k0 + kq*4);
      *(float4*)&As[rr*40 + kq*4] = av;
    }
    #pragma unroll
    for(int p=0;p<4;p++){              // stage B 32x128 via float4
      int idx = p*256 + t;             // 0..1023
      int kk = idx >> 5, cq = idx & 31;
      float4 bv = *(const float4*)(Wm + (size_t)(k0+kk)*128 + cq*4);
      *(float4*)&Bs[kk*128 + cq*4] = bv;
    }
    __syncthreads();
    #pragma unroll 4
    for(int kk=0;kk<32;kk+=2){
      float4 b0 = *(float4*)&Bs[kk*128 + tx*4];
      float4 b1 = *(float4*)&Bs[(kk+1)*128 + tx*4];
      #pragma unroll
      for(int j=0;j<8;j++){
        float2 a = *(float2*)&As[(ty*8+j)*40 + kk];
        acc[j][0] += a.x*b0.x; acc[j][1] += a.x*b0.y;
        acc[j][2] += a.x*b0.z; acc[j][3] += a.x*b0.w;
        acc[j][0] += a.y*b1.x; acc[j][1] += a.y*b1.y;
        acc[j][2] += a.y*b1.z; acc[j][3] += a.y*b1.w;
      }
    }
    __syncthreads();
  }
  // epilogue: bias + BN + ReLU, scatter-write raw rows, score = tanh(dot*invnorm)
  float invn = invn_p[0];
  float bi[4], scv[4], bt[4], mn[4], pwv[4];
  #pragma unroll
  for(int i=0;i<4;i++){
    int c = tx*4+i;
    bi[i]  = bias[c];
    scv[i] = gamma[c] * (1.0f/sqrtf(var[c] + BNEPS));
    bt[i]  = beta[c];
    mn[i]  = mean[c];
    pwv[i] = pw[c];
  }
  #pragma unroll
  for(int j=0;j<8;j++){
    int row = r0 + ty*8 + j;
    int orig = olist ? olist[row] : row;
    float v0 = fmaxf((acc[j][0]+bi[0]-mn[0])*scv[0]+bt[0], 0.f);
    float v1 = fmaxf((acc[j][1]+bi[1]-mn[1])*scv[1]+bt[1], 0.f);
    float v2 = fmaxf((acc[j][2]+bi[2]-mn[2])*scv[2]+bt[2], 0.f);
    float v3 = fmaxf((acc[j][3]+bi[3]-mn[3])*scv[3]+bt[3], 0.f);
    float4 o; o.x=v0; o.y=v1; o.z=v2; o.w=v3;
    *(float4*)(hout + (size_t)orig*HDIM + tx*4) = o;
    float p = v0*pwv[0]+v1*pwv[1]+v2*pwv[2]+v3*pwv[3];
    #pragma unroll
    for(int m=16;m>=1;m>>=1) p += __shfl_xor(p, m, 64);
    if(tx==0) score[row] = tanhf(p * invn);
  }
}

// ---------------- per-graph top-k: bitonic sort (score desc, idx asc) ----------------
// Compose orig-id node list for next layer; zero dinvz+gsc of dropped nodes.
__global__ __launch_bounds__(512) void k_topk(int n, int k, int P,
    const float* __restrict__ score, const int* __restrict__ curlist,
    float* __restrict__ vals, int* __restrict__ nextlist,
    float* __restrict__ dinvz, float* __restrict__ gsc){
  int g = blockIdx.x, t = threadIdx.x;
  __shared__ float s[1024];
  __shared__ int  id[1024];
  for(int i=t;i<P;i+=512){
    s[i]  = (i<n) ? score[g*n+i] : -FLT_MAX;
    id[i] = i;
  }
  __syncthreads();
  for(int k2=2;k2<=P;k2<<=1){
    for(int j=k2>>1;j>0;j>>=1){
      for(int i=t;i<P;i+=512){
        int ixj = i ^ j;
        if(ixj > i){
          bool desc = ((i & k2) == 0);
          float si = s[i], sx = s[ixj];
          int ii = id[i], ix = id[ixj];
          bool pre = (si > sx) || (si == sx && ii < ix);  // i precedes in desc order
          if(desc ? !pre : pre){ s[i]=sx; s[ixj]=si; id[i]=ix; id[ixj]=ii; }
        }
      }
      __syncthreads();
    }
  }
  for(int i=t;i<n;i+=512){
    int idx = id[i];
    int orig = curlist ? curlist[g*n+idx] : (g*NPG0 + idx);
    if(i<k){
      vals[g*k+i]=s[i]; nextlist[g*k+i]=orig;
    } else {
      dinvz[orig] = 0.f;               // node dies (alive sets nest)
      gsc[orig]   = 0.f;
    }
  }
}

// ---------------- pool partials + next-layer degree + gsc ----------------
// Pool: half-wave (32 lanes x float4 = full 128-col row) -> 2 rows in flight per wave.
// Deg: quarter-wave per row (16 lanes ~ avg degree) -> 4 rows in flight per wave.
// Each (chunk,graph) block writes a PRIVATE partial slot (no atomics, no init needed).
__global__ __launch_bounds__(256) void k_gpd(int k, int do_deg,
    const float* __restrict__ hraw, const float* __restrict__ vals,
    const int* __restrict__ nextlist,
    float* __restrict__ sumst, float* __restrict__ maxst,
    const int* __restrict__ rp, const long long* __restrict__ ec,
    float* __restrict__ dinvz, float* __restrict__ gsc){
  int g = blockIdx.x & 63;
  int chunk = blockIdx.x >> 6;               // 0..POOL_NB-1
  int wid = threadIdx.x >> 6, lane = threadIdx.x & 63;
  int ww = chunk*4 + wid;                    // wave id within graph: 0..POOL_NB*4-1
  const int half = lane >> 5, sl32 = lane & 31;
  const int qw   = lane >> 4, sl16 = lane & 15;
  const int NH = POOL_NB*4*2;                // half-waves per graph
  float4 psum; psum.x=0.f; psum.y=0.f; psum.z=0.f; psum.w=0.f;
  float4 pmax; pmax.x=-FLT_MAX; pmax.y=-FLT_MAX; pmax.z=-FLT_MAX; pmax.w=-FLT_MAX;
  for(int j = ww*2 + half; j < k; j += NH){
    float v = vals[g*k+j];
    int d = nextlist[g*k+j];
    float4 hv = *(const float4*)(hraw + (size_t)d*HDIM + 4*sl32);
    float4 o; o.x=hv.x*v; o.y=hv.y*v; o.z=hv.z*v; o.w=hv.w*v;
    psum.x+=o.x; psum.y+=o.y; psum.z+=o.z; psum.w+=o.w;
    pmax.x=fmaxf(pmax.x,o.x); pmax.y=fmaxf(pmax.y,o.y);
    pmax.z=fmaxf(pmax.z,o.z); pmax.w=fmaxf(pmax.w,o.w);
  }
  if(do_deg){
    const int NQ = POOL_NB*4*4;              // quarter-waves per graph
    for(int j = ww*4 + qw; j < k; j += NQ){
      int d  = nextlist[g*k + j];
      int ld = d - g*NPG0;
      int e0 = rp[g*RPS+ld], e1 = rp[g*RPS+ld+1];
      float deg = 0.f;
      for(int b=e0+sl16; b<e1; b+=16){
        long long rec = ec[(size_t)g*EG + b];
        int s = (int)(rec & 0xffffffffLL);
        float w = __int_as_float((int)(rec>>32));
        if(dinvz[s] != 0.f) deg += w;
      }
      #pragma unroll
      for(int o=8;o>0;o>>=1) deg += __shfl_xor(deg, o, 64);  // within 16-lane group
      if(sl16==0){
        float dv = 1.0f / sqrtf(deg + 1.0f);
        dinvz[d] = dv;
        gsc[d] = dv * vals[g*k+j];
      }
    }
  }
  // cross-half reduce (each half covered all 128 features for its row subset)
  psum.x += __shfl_xor(psum.x, 32, 64); psum.y += __shfl_xor(psum.y, 32, 64);
  psum.z += __shfl_xor(psum.z, 32, 64); psum.w += __shfl_xor(psum.w, 32, 64);
  pmax.x = fmaxf(pmax.x, __shfl_xor(pmax.x, 32, 64));
  pmax.y = fmaxf(pmax.y, __shfl_xor(pmax.y, 32, 64));
  pmax.z = fmaxf(pmax.z, __shfl_xor(pmax.z, 32, 64));
  pmax.w = fmaxf(pmax.w, __shfl_xor(pmax.w, 32, 64));
  __shared__ float ss[4][128];
  __shared__ float sm[4][128];
  if(half==0){
    *(float4*)&ss[wid][4*sl32] = psum;
    *(float4*)&sm[wid][4*sl32] = pmax;
  }
  __syncthreads();
  int t = threadIdx.x;
  if(t < 128){
    float s = (ss[0][t]+ss[1][t]) + (ss[2][t]+ss[3][t]);
    float m = fmaxf(fmaxf(sm[0][t], sm[1][t]), fmaxf(sm[2][t], sm[3][t]));
    sumst[(size_t)(chunk*NGR + g)*HDIM + t] = s;
    maxst[(size_t)(chunk*NGR + g)*HDIM + t] = m;
  }
}

// ---------------- MLP head (folds 6 layers x POOL_NB chunk partials) ----------------
__global__ __launch_bounds__(512) void k_head(const float* __restrict__ sumstage,
    const float* __restrict__ maxstage,
    const float* __restrict__ d1w, const float* __restrict__ d1b,
    const float* __restrict__ d2w, const float* __restrict__ d2b, float* __restrict__ out){
  const float kinv[6] = {1.f/800.f, 1.f/640.f, 1.f/512.f, 1.f/410.f, 1.f/328.f, 1.f/263.f};
  int g = blockIdx.x, j = threadIdx.x;
  __shared__ float fl[256];
  __shared__ float hd[512];
  if(j < 128){
    float s = 0.f;
    #pragma unroll
    for(int l=0;l<6;l++){
      float ls = 0.f;
      for(int c=0;c<POOL_NB;c++)
        ls += sumstage[(size_t)((l*POOL_NB + c)*NGR + g)*HDIM + j];
      s += ls * kinv[l];
    }
    fl[j] = s;
  } else if(j < 256){
    int f = j - 128;
    float m = 0.f;
    #pragma unroll
    for(int l=0;l<6;l++){
      float lm = -FLT_MAX;
      for(int c=0;c<POOL_NB;c++)
        lm = fmaxf(lm, maxstage[(size_t)((l*POOL_NB + c)*NGR + g)*HDIM + f]);
      m += lm;
    }
    fl[j] = m;
  }
  __syncthreads();
  float acc = d1b[j];
  for(int i=0;i<256;i++) acc += fl[i]*d1w[i*512+j];
  hd[j] = fmaxf(acc, 0.f);
  __syncthreads();
  if(j < 10){
    float a = d2b[j];
    for(int i=0;i<512;i++) a += hd[i]*d2w[i*10+j];
    out[g*10+j] = a;
  }
}

extern "C" void kernel_launch(void* const* d_in, const int* in_sizes, int n_in,
                              void* d_out, int out_size, void* d_ws, size_t ws_size,
                              hipStream_t stream) {
  const float* x    = (const float*)d_in[0];
  const int* ei     = (const int*)d_in[1];
  const float* ew   = (const float*)d_in[3];
  const float* conv1w = (const float*)d_in[4];
  const float* convw  = (const float*)d_in[5];
  const float* convb  = (const float*)d_in[6];
  const float* bng    = (const float*)d_in[7];
  const float* bnb    = (const float*)d_in[8];
  const float* bnm    = (const float*)d_in[9];
  const float* bnv    = (const float*)d_in[10];
  const float* poolw  = (const float*)d_in[11];
  const float* d1w    = (const float*)d_in[12];
  const float* d1b    = (const float*)d_in[13];
  const float* d2w    = (const float*)d_in[14];
  const float* d2b    = (const float*)d_in[15];
  float* out = (float*)d_out;

  char* w = (char*)d_ws;
  float* horig = (float*)w; w += (size_t)64000*128*4;   // raw gemm outputs by ORIGINAL node id
  float* hc    = (float*)w; w += (size_t)64000*128*4;   // agg output compact (gemm A input)
  float* agg0  = (float*)w; w += (size_t)64000*64*4;    // layer-0 aggregation (64 cols)
  long long* ec = (long long*)w; w += (size_t)NE*8;     // static (w, src_orig), dst-bucketed
  int*   rp    = (int*)w;   w += (size_t)NGR*RPS*4;
  int*   pcnt  = (int*)w;   w += (size_t)256*NPG0*4;
  float* pdeg  = (float*)w; w += (size_t)256*NPG0*4;
  float* dinvz = (float*)w; w += (size_t)64000*4;       // 0 == node dead (alive indicator)
  float* gsc   = (float*)w; w += (size_t)64000*4;       // dinv_new * topk_val (0 == dead)
  float* score = (float*)w; w += (size_t)64000*4;
  float* vals  = (float*)w; w += (size_t)51200*4;
  int*   listA = (int*)w;   w += (size_t)51200*4;
  int*   listB = (int*)w;   w += (size_t)51200*4;
  float* invno = (float*)w; w += 64;
  float* sumstage = (float*)w; w += (size_t)6*POOL_NB*NGR*HDIM*4;
  float* maxstage = (float*)w; w += (size_t)6*POOL_NB*NGR*HDIM*4;

  k_invnorm<<<6,128,0,stream>>>(poolw, invno);

  const int ns[6]={1000,800,640,512,410,328};
  const int ks[6]={800,640,512,410,328,263};

  // ---- one-time CSR build (original ids): count partials, then fused scan+scatter ----
  k_count0<<<256,256,0,stream>>>(ei+NE, ew, pcnt, pdeg);
  k_build<<<64,1024,0,stream>>>(pcnt, pdeg, ei, ei+NE, ew, rp, dinvz, gsc, ec);

  // ---- layer 0 (input = x, 64 cols) ----
  k_agg<1><<<64*32,256,0,stream>>>(1000, nullptr, rp, ec, dinvz, gsc, x, agg0);
  k_gemm<64><<<1000,256,0,stream>>>(agg0, conv1w, convb, bng, bnb, bnm, bnv, poolw, invno,
                                    nullptr, horig, score);
  k_topk<<<64,512,0,stream>>>(1000, 800, 1024, score, nullptr, vals, listA, dinvz, gsc);
  k_gpd<<<64*POOL_NB,256,0,stream>>>(800, 1, horig, vals, listA,
                                     sumstage, maxstage, rp, ec, dinvz, gsc);

  // ---- layers 1..5 ----
  int* cur = listA; int* nxt = listB;
  for(int i=1;i<6;i++){
    int n = ns[i], k = ks[i];
    k_agg<0><<<64*32,256,0,stream>>>(n, cur, rp, ec, dinvz, gsc, horig, hc);
    k_gemm<128><<<n,256,0,stream>>>(hc, convw+(size_t)(i-1)*128*128, convb+i*128, bng+i*128,
                                    bnb+i*128, bnm+i*128, bnv+i*128, poolw+i*128, invno+i,
                                    cur, horig, score);
    int P = (n > 512) ? 1024 : 512;
    k_topk<<<64,512,0,stream>>>(n, k, P, score, cur, vals, nxt, dinvz, gsc);
    k_gpd<<<64*POOL_NB,256,0,stream>>>(k, (i<5)?1:0, horig, vals, nxt,
                                       sumstage + (size_t)i*POOL_NB*NGR*HDIM,
                                       maxstage + (size_t)i*POOL_NB*NGR*HDIM,
                                       rp, ec, dinvz, gsc);
    int* tmp = cur; cur = nxt; nxt = tmp;
  }

  k_head<<<64,512,0,stream>>>(sumstage, maxstage, d1w, d1b, d2w, d2b, out);
}